// Round 14
// baseline (692.065 us; speedup 1.0000x reference)
//
#include <hip/hip_runtime.h>

typedef float f32x4 __attribute__((ext_vector_type(4)));
typedef _Float16 f16x8 __attribute__((ext_vector_type(8)));

#define NBATCH 32
#define NPTS   16384
#define W_TOT  197888
#define B_TOT  1027

// ws layout (halves):
//   [0)         W hi frags, hidden layers: 32 b * 3 l * 65536
//   [6291456)   W lo frags (layers 0,1 only)
//   [12582912)  W4 hi frags: 32 b * 8 s * 512
#define WLO_OFF 6291456
#define W4_OFF  12582912
#define WS_NEEDED 25427968ull

// out layout (floats)
#define OUT_COORDS 1572864
#define OUT_W      2621440
#define OUT_B      8953856
#define OUT_LAT    8986720

// sin(30*x) via v_sin_f32 (input in revolutions): t = x*30/(2pi), fract-reduced
static __device__ __forceinline__ float fast_sin30(float x) {
    float t = x * 4.774648292756860f;
#if __has_builtin(__builtin_amdgcn_fractf)
    t = __builtin_amdgcn_fractf(t);
#else
    t -= floorf(t);
#endif
    return __builtin_amdgcn_sinf(t);
}

static __device__ __forceinline__ void sin_split_pk(float a0, float a1,
                                                    unsigned& uh, unsigned& ul) {
    float s0 = fast_sin30(a0), s1 = fast_sin30(a1);
    auto hp = __builtin_amdgcn_cvt_pkrtz(s0, s1);
    float l0 = s0 - (float)hp[0];
    float l1 = s1 - (float)hp[1];
    auto lp = __builtin_amdgcn_cvt_pkrtz(l0, l1);
    uh = __builtin_bit_cast(unsigned, hp);
    ul = __builtin_bit_cast(unsigned, lp);
}

static __device__ __forceinline__ unsigned sin_pk2(float a0, float a1) {
    float s0 = fast_sin30(a0), s1 = fast_sin30(a1);
    auto hp = __builtin_amdgcn_cvt_pkrtz(s0, s1);
    return __builtin_bit_cast(unsigned, hp);
}

// ---- pre-kernel: split W into hi/lo fp16 fragments in MFMA layout ----
__global__ void make_wfrags(const float* __restrict__ w, _Float16* __restrict__ wf) {
    int idx = blockIdx.x * 256 + threadIdx.x;
    if (idx < 6291456) {
        int batch = idx / 196608;
        int rem   = idx - batch * 196608;
        int layer = rem >> 16;
        int rem2  = rem & 65535;
        int s     = rem2 >> 13;
        int rem3  = rem2 & 8191;
        int ntile = rem3 >> 9;
        int rem4  = rem3 & 511;
        int lane  = rem4 >> 3, r = rem4 & 7;
        int col = ntile * 16 + (lane & 15);
        int k   = s * 32 + 4 * (lane >> 4) + (r & 3) + 16 * (r >> 2);
        float v = w[(size_t)batch * W_TOT + 512 + layer * 65536 + col * 256 + k];
        _Float16 h = (_Float16)v;
        wf[idx] = h;
        if (layer < 2)
            wf[WLO_OFF + idx] = (_Float16)(v - (float)h);
    } else if (idx < 6291456 + 131072) {
        int i4 = idx - 6291456;
        int batch = i4 >> 12;
        int rem   = i4 & 4095;
        int s     = rem >> 9;
        int rem2  = rem & 511;
        int lane  = rem2 >> 3, r = rem2 & 7;
        int col = lane & 15;
        int k   = s * 32 + 4 * (lane >> 4) + (r & 3) + 16 * (r >> 2);
        float v = (col < 3) ? w[(size_t)batch * W_TOT + 197120 + col * 256 + k] : 0.0f;
        wf[W4_OFF + i4] = (_Float16)v;
    }
}

// act LDS layout (stream): IDX(p,s,c,e) = s*2048 + c*512 + p*8 + e
//   s = f>>5, c = (f>>2)&3, e = ((f>>4)&1)*4 + (f&3)

// ---- phase pieces (no barriers inside; caller owns __syncthreads) ----

static __device__ __forceinline__ void l0_entry(
    _Float16* __restrict__ Ahi, _Float16* __restrict__ Alo,
    const float* __restrict__ coords, const float* __restrict__ wb,
    const float* __restrict__ bb, int batch, int n0, int tg)
{
    int p = tg >> 2, fb = (tg & 3) * 64;
    float2 c = ((const float2*)coords)[(size_t)batch * NPTS + n0 + p];
    #pragma unroll 8
    for (int j2 = 0; j2 < 64; j2 += 2) {
        int f = fb + j2;
        float4 wv = *(const float4*)(wb + 2 * f);
        float b0 = bb[f], b1 = bb[f + 1];
        float u0 = fmaf(c.x, wv.x, fmaf(c.y, wv.y, b0));
        float u1 = fmaf(c.x, wv.z, fmaf(c.y, wv.w, b1));
        unsigned uh, ul;
        sin_split_pk(u0, u1, uh, ul);
        int sf = f >> 5, cf = (f >> 2) & 3, ef = ((f >> 4) & 1) * 4 + (f & 3);
        int idx = sf * 2048 + cf * 512 + p * 8 + ef;
        *(unsigned*)&Ahi[idx] = uh;
        *(unsigned*)&Alo[idx] = ul;
    }
}

template<int NPASS>
static __device__ __forceinline__ void mfma_layer(
    f32x4 (&acc)[4][4],
    const _Float16* __restrict__ Ahi, const _Float16* __restrict__ Alo,
    const _Float16* __restrict__ whf, const float* __restrict__ bias_base,
    int wn, int lane, int r15, int g)
{
    const _Float16* wbase = whf + (wn * 4) * 512 + lane * 8;
    #pragma unroll
    for (int mt = 0; mt < 4; ++mt) {
        float4 bv = *(const float4*)(bias_base + (wn * 4 + mt) * 16 + 4 * g);
        f32x4 bi = {bv.x, bv.y, bv.z, bv.w};
        #pragma unroll
        for (int nt = 0; nt < 4; ++nt) acc[mt][nt] = bi;
    }
    __builtin_amdgcn_s_setprio(1);
    #pragma unroll
    for (int s = 0; s < 8; ++s) {
        f16x8 bh[4], bl[4];
        #pragma unroll
        for (int nt = 0; nt < 4; ++nt) {
            int idx = s * 2048 + g * 512 + (nt * 16 + r15) * 8;
            bh[nt] = *(const f16x8*)&Ahi[idx];
            bl[nt] = *(const f16x8*)&Alo[idx];
        }
        #pragma unroll
        for (int mt = 0; mt < 4; ++mt) {
            const _Float16* pb = wbase + s * 8192 + mt * 512;
            f16x8 wh = *(const f16x8*)pb;
            f16x8 wl;
            if (NPASS >= 3) wl = *(const f16x8*)(pb + WLO_OFF);
            #pragma unroll
            for (int nt = 0; nt < 4; ++nt) {
                acc[mt][nt] = __builtin_amdgcn_mfma_f32_16x16x32_f16(wh, bh[nt], acc[mt][nt], 0, 0, 0);
                acc[mt][nt] = __builtin_amdgcn_mfma_f32_16x16x32_f16(wh, bl[nt], acc[mt][nt], 0, 0, 0);
                if (NPASS >= 3)
                    acc[mt][nt] = __builtin_amdgcn_mfma_f32_16x16x32_f16(wl, bh[nt], acc[mt][nt], 0, 0, 0);
            }
        }
    }
    __builtin_amdgcn_s_setprio(0);
}

template<bool WRITE_LO>
static __device__ __forceinline__ void epi_layer(
    const f32x4 (&acc)[4][4],
    _Float16* __restrict__ Ahi, _Float16* __restrict__ Alo,
    int wn, int r15, int g)
{
    #pragma unroll
    for (int nt = 0; nt < 4; ++nt) {
        int p = nt * 16 + r15;
        #pragma unroll
        for (int a = 0; a < 2; ++a) {
            uint4 ch, cl;
            if (WRITE_LO) {
                sin_split_pk(acc[2*a  ][nt][0], acc[2*a  ][nt][1], ch.x, cl.x);
                sin_split_pk(acc[2*a  ][nt][2], acc[2*a  ][nt][3], ch.y, cl.y);
                sin_split_pk(acc[2*a+1][nt][0], acc[2*a+1][nt][1], ch.z, cl.z);
                sin_split_pk(acc[2*a+1][nt][2], acc[2*a+1][nt][3], ch.w, cl.w);
            } else {
                ch.x = sin_pk2(acc[2*a  ][nt][0], acc[2*a  ][nt][1]);
                ch.y = sin_pk2(acc[2*a  ][nt][2], acc[2*a  ][nt][3]);
                ch.z = sin_pk2(acc[2*a+1][nt][0], acc[2*a+1][nt][1]);
                ch.w = sin_pk2(acc[2*a+1][nt][2], acc[2*a+1][nt][3]);
            }
            int idx = (2 * wn + a) * 2048 + g * 512 + p * 8;
            *(uint4*)&Ahi[idx] = ch;
            if (WRITE_LO) *(uint4*)&Alo[idx] = cl;
        }
    }
}

static __device__ __forceinline__ void l4_out(
    const _Float16* __restrict__ Ahi, const _Float16* __restrict__ w4,
    const float* __restrict__ bb, float* __restrict__ out,
    int batch, int n0, int wn, int lane, int r15, int g)
{
    f32x4 acc4 = {};
    #pragma unroll
    for (int s = 0; s < 8; ++s) {
        int p = wn * 16 + r15;
        int idx = s * 2048 + g * 512 + p * 8;
        f16x8 bh = *(const f16x8*)&Ahi[idx];
        f16x8 w4f = *(const f16x8*)(w4 + s * 512 + lane * 8);
        acc4 = __builtin_amdgcn_mfma_f32_16x16x32_f16(w4f, bh, acc4, 0, 0, 0);
    }
    if (g == 0) {
        int p = wn * 16 + r15;
        float* po = out + ((size_t)batch * NPTS + n0 + p) * 3;
        #pragma unroll
        for (int j = 0; j < 3; ++j)
            po[j] = acc4[j] + bb[1024 + j];
    }
}

// 512 threads = 2 groups x 4 waves. Group A (waves 0-3) owns pts [n0,+64),
// group B (waves 4-7) owns [n0+64,+64), each with private 64KB LDS.
// Groups run the layer pipeline shifted by one phase: while A does MFMA(Lk),
// B does epilogue(Lk-1) -> matrix and VALU pipes both fed deterministically.
__global__ __launch_bounds__(512, 2)
void siren_mfma(const float* __restrict__ coords,
                const float* __restrict__ w,
                const float* __restrict__ b,
                const _Float16* __restrict__ wf,
                float* __restrict__ out)
{
    __shared__ _Float16 AhiA[64 * 256];
    __shared__ _Float16 AloA[64 * 256];
    __shared__ _Float16 AhiB[64 * 256];
    __shared__ _Float16 AloB[64 * 256];

    const int bid = blockIdx.x, batch = bid >> 7, chunk = bid & 127;
    const int t = threadIdx.x, wave = t >> 6, lane = t & 63;
    const int r15 = lane & 15, g = lane >> 4;
    const bool gB = wave >= 4;
    const int wn = wave & 3;
    const int tg = t & 255;
    const int n0A = chunk * 128, n0B = n0A + 64;

    const float* wb = w + (size_t)batch * W_TOT;
    const float* bb = b + (size_t)batch * B_TOT;
    const _Float16* whf0 = wf + (size_t)(batch * 3 + 0) * 65536;
    const _Float16* whf1 = wf + (size_t)(batch * 3 + 1) * 65536;
    const _Float16* whf2 = wf + (size_t)(batch * 3 + 2) * 65536;
    const _Float16* w4   = wf + W4_OFF + batch * 4096;

    f32x4 acc[4][4];

    // P0: A entry
    if (!gB) l0_entry(AhiA, AloA, coords, wb, bb, batch, n0A, tg);
    __syncthreads();
    // P1: A M(L1) | B entry
    if (!gB) mfma_layer<3>(acc, AhiA, AloA, whf0, bb + 256, wn, lane, r15, g);
    else     l0_entry(AhiB, AloB, coords, wb, bb, batch, n0B, tg);
    __syncthreads();
    // P2: A E(L1) | B M(L1)
    if (!gB) epi_layer<true>(acc, AhiA, AloA, wn, r15, g);
    else     mfma_layer<3>(acc, AhiB, AloB, whf0, bb + 256, wn, lane, r15, g);
    __syncthreads();
    // P3: A M(L2) | B E(L1)
    if (!gB) mfma_layer<3>(acc, AhiA, AloA, whf1, bb + 512, wn, lane, r15, g);
    else     epi_layer<true>(acc, AhiB, AloB, wn, r15, g);
    __syncthreads();
    // P4: A E(L2) | B M(L2)
    if (!gB) epi_layer<true>(acc, AhiA, AloA, wn, r15, g);
    else     mfma_layer<3>(acc, AhiB, AloB, whf1, bb + 512, wn, lane, r15, g);
    __syncthreads();
    // P5: A M(L3) | B E(L2)
    if (!gB) mfma_layer<2>(acc, AhiA, AloA, whf2, bb + 768, wn, lane, r15, g);
    else     epi_layer<true>(acc, AhiB, AloB, wn, r15, g);
    __syncthreads();
    // P6: A E(L3) | B M(L3)
    if (!gB) epi_layer<false>(acc, AhiA, AloA, wn, r15, g);
    else     mfma_layer<2>(acc, AhiB, AloB, whf2, bb + 768, wn, lane, r15, g);
    __syncthreads();
    // P7: A L4+store | B E(L3)
    if (!gB) l4_out(AhiA, w4, bb, out, batch, n0A, wn, lane, r15, g);
    else     epi_layer<false>(acc, AhiB, AloB, wn, r15, g);
    __syncthreads();
    // P8: B L4+store
    if (gB) l4_out(AhiB, w4, bb, out, batch, n0B, wn, lane, r15, g);
}

// ---- fallback fp32 kernel (used only if ws too small) ----
__global__ __launch_bounds__(256, 2)
void siren_fwd_fp32(const float* __restrict__ coords,
                    const float* __restrict__ w,
                    const float* __restrict__ b,
                    float* __restrict__ out)
{
    __shared__ float A[256][64 + 4];
    const int bid = blockIdx.x, batch = bid >> 8, tile = bid & 255;
    const int t = threadIdx.x, n0 = tile * 64;
    const float* wb = w + (size_t)batch * W_TOT;
    const float* bb = b + (size_t)batch * B_TOT;
    const float2* c2 = (const float2*)(coords + (size_t)(batch * NPTS + n0) * 2);
    {
        const float w0 = wb[t * 2 + 0], w1 = wb[t * 2 + 1], b0 = bb[t];
        for (int p = 0; p < 64; ++p) {
            const float2 c = c2[p];
            A[t][p] = fast_sin30(fmaf(c.x, w0, fmaf(c.y, w1, b0)));
        }
    }
    __syncthreads();
    for (int li = 0; li < 3; ++li) {
        const float* Wl = wb + 512 + li * 65536 + t * 256;
        const float bo = bb[256 + li * 256 + t];
        float res[64];
        for (int pb = 0; pb < 2; ++pb) {
            float acc[32];
            #pragma unroll
            for (int i = 0; i < 32; ++i) acc[i] = bo;
            for (int k = 0; k < 256; k += 4) {
                const float4 wv = *(const float4*)(Wl + k);
                #pragma unroll
                for (int kk = 0; kk < 4; ++kk) {
                    const float wk = (&wv.x)[kk];
                    const float* ar = &A[k + kk][pb * 32];
                    #pragma unroll
                    for (int i = 0; i < 32; i += 4) {
                        const float4 a4 = *(const float4*)(ar + i);
                        acc[i + 0] = fmaf(a4.x, wk, acc[i + 0]);
                        acc[i + 1] = fmaf(a4.y, wk, acc[i + 1]);
                        acc[i + 2] = fmaf(a4.z, wk, acc[i + 2]);
                        acc[i + 3] = fmaf(a4.w, wk, acc[i + 3]);
                    }
                }
            }
            #pragma unroll
            for (int i = 0; i < 32; ++i) res[pb * 32 + i] = fast_sin30(acc[i]);
        }
        __syncthreads();
        for (int p = 0; p < 64; p += 4)
            *(float4*)&A[t][p] = make_float4(res[p], res[p+1], res[p+2], res[p+3]);
        __syncthreads();
    }
    if (t < 192) {
        const int o = t >> 6, p = t & 63;
        const float* W4 = wb + 197120 + o * 256;
        float acc = bb[1024 + o];
        for (int k = 0; k < 256; k += 4) {
            const float4 wv = *(const float4*)(W4 + k);
            acc = fmaf(A[k+0][p], wv.x, acc);
            acc = fmaf(A[k+1][p], wv.y, acc);
            acc = fmaf(A[k+2][p], wv.z, acc);
            acc = fmaf(A[k+3][p], wv.w, acc);
        }
        out[(size_t)(batch * NPTS + n0 + p) * 3 + o] = acc;
    }
}

extern "C" void kernel_launch(void* const* d_in, const int* in_sizes, int n_in,
                              void* d_out, int out_size, void* d_ws, size_t ws_size,
                              hipStream_t stream)
{
    const float* coords = (const float*)d_in[0];
    const float* w      = (const float*)d_in[1];
    const float* bvec   = (const float*)d_in[2];
    const float* latent = (const float*)d_in[3];
    float* out = (float*)d_out;

    if (ws_size >= WS_NEEDED) {
        _Float16* wf = (_Float16*)d_ws;
        make_wfrags<<<25088, 256, 0, stream>>>(w, wf);
        siren_mfma<<<NBATCH * (NPTS / 128), 512, 0, stream>>>(coords, w, bvec, wf, out);
    } else {
        siren_fwd_fp32<<<NBATCH * (NPTS / 64), 256, 0, stream>>>(coords, w, bvec, out);
    }

    hipMemcpyAsync(out + OUT_COORDS, coords, (size_t)1048576 * sizeof(float),
                   hipMemcpyDeviceToDevice, stream);
    hipMemcpyAsync(out + OUT_W,      w,      (size_t)6332416 * sizeof(float),
                   hipMemcpyDeviceToDevice, stream);
    hipMemcpyAsync(out + OUT_B,      bvec,   (size_t)32864   * sizeof(float),
                   hipMemcpyDeviceToDevice, stream);
    hipMemcpyAsync(out + OUT_LAT,    latent, (size_t)8192    * sizeof(float),
                   hipMemcpyDeviceToDevice, stream);
}

// Round 15
// 578.675 us; speedup vs baseline: 1.1959x; 1.1959x over previous
//
#include <hip/hip_runtime.h>

typedef float f32x4 __attribute__((ext_vector_type(4)));
typedef _Float16 f16x8 __attribute__((ext_vector_type(8)));

#define NBATCH 32
#define NPTS   16384
#define W_TOT  197888
#define B_TOT  1027

// ws layout (halves):
//   [0)         W hi frags, hidden layers: 32 b * 3 l * 65536
//   [6291456)   W lo frags (layers 0,1 only)
//   [12582912)  W4 hi frags: 32 b * 8 s * 512
#define WLO_OFF 6291456
#define W4_OFF  12582912
#define WS_NEEDED 25427968ull

// out layout (floats)
#define OUT_COORDS 1572864
#define OUT_W      2621440
#define OUT_B      8953856
#define OUT_LAT    8986720

// sin(30*x) via v_sin_f32 (input in revolutions): t = x*30/(2pi), fract-reduced
static __device__ __forceinline__ float fast_sin30(float x) {
    float t = x * 4.774648292756860f;
#if __has_builtin(__builtin_amdgcn_fractf)
    t = __builtin_amdgcn_fractf(t);
#else
    t -= floorf(t);
#endif
    return __builtin_amdgcn_sinf(t);
}

// sin + fp16 hi/lo split for a pair of values, packed via v_cvt_pkrtz
static __device__ __forceinline__ void sin_split_pk(float a0, float a1,
                                                    unsigned& uh, unsigned& ul) {
    float s0 = fast_sin30(a0), s1 = fast_sin30(a1);
    auto hp = __builtin_amdgcn_cvt_pkrtz(s0, s1);
    float l0 = s0 - (float)hp[0];
    float l1 = s1 - (float)hp[1];
    auto lp = __builtin_amdgcn_cvt_pkrtz(l0, l1);
    uh = __builtin_bit_cast(unsigned, hp);
    ul = __builtin_bit_cast(unsigned, lp);
}

// sin + fp16 pack, hi only (for layers whose consumer never reads act-lo)
static __device__ __forceinline__ unsigned sin_pk2(float a0, float a1) {
    float s0 = fast_sin30(a0), s1 = fast_sin30(a1);
    auto hp = __builtin_amdgcn_cvt_pkrtz(s0, s1);
    return __builtin_bit_cast(unsigned, hp);
}

// ---- pre-kernel: split W into hi/lo fp16 fragments in MFMA layout ----
// frag element order: [batch][layer][s][tile16][lane][r]
// idx16 = tile*16 + (lane&15); k = s*32 + 4*(lane>>4) + (r&3) + 16*(r>>2)
__global__ void make_wfrags(const float* __restrict__ w, _Float16* __restrict__ wf) {
    int idx = blockIdx.x * 256 + threadIdx.x;
    if (idx < 6291456) {
        int batch = idx / 196608;
        int rem   = idx - batch * 196608;
        int layer = rem >> 16;
        int rem2  = rem & 65535;
        int s     = rem2 >> 13;
        int rem3  = rem2 & 8191;
        int ntile = rem3 >> 9;
        int rem4  = rem3 & 511;
        int lane  = rem4 >> 3, r = rem4 & 7;
        int col = ntile * 16 + (lane & 15);
        int k   = s * 32 + 4 * (lane >> 4) + (r & 3) + 16 * (r >> 2);
        float v = w[(size_t)batch * W_TOT + 512 + layer * 65536 + col * 256 + k];
        _Float16 h = (_Float16)v;
        wf[idx] = h;
        if (layer < 2)   // W-lo consumed only by 3-pass layers (hidden 0, 1)
            wf[WLO_OFF + idx] = (_Float16)(v - (float)h);
    } else if (idx < 6291456 + 131072) {
        int i4 = idx - 6291456;
        int batch = i4 >> 12;
        int rem   = i4 & 4095;
        int s     = rem >> 9;
        int rem2  = rem & 511;
        int lane  = rem2 >> 3, r = rem2 & 7;
        int col = lane & 15;
        int k   = s * 32 + 4 * (lane >> 4) + (r & 3) + 16 * (r >> 2);
        float v = (col < 3) ? w[(size_t)batch * W_TOT + 197120 + col * 256 + k] : 0.0f;
        wf[W4_OFF + i4] = (_Float16)v;
    }
}

// act LDS layout, "stream" form (conflict-free, no swizzle):
//   half index IDX(p, s, c, e) = s*2048 + c*512 + p*8 + e
//   where s = K-chunk (f>>5), c = 8-half group ((f>>2)&3), e = ((f>>4)&1)*4 + (f&3)
// B-frag read for (point p, K-chunk s, group g): ONE b128 at IDX(p,s,g,0).

// One hidden layer (256->256). NPASS: 3 = hh+hl+lh, 2 = hh+hl, 1 = hh only.
// WRITE_LO: whether the epilogue stores act-lo (needed iff next layer reads bl).
template<int NPASS, bool WRITE_LO>
static __device__ __forceinline__ void hidden_layer(
    _Float16* __restrict__ Ahi, _Float16* __restrict__ Alo,
    const _Float16* __restrict__ whf, const float* __restrict__ bias_base,
    int wn, int lane, int r15, int g)
{
    const _Float16* wbase = whf + (wn * 4) * 512 + lane * 8;

    // acc[mt][nt]: mt = feat tile (wn*4+mt), nt = point tile; bias init
    f32x4 acc[4][4];
    #pragma unroll
    for (int mt = 0; mt < 4; ++mt) {
        float4 bv = *(const float4*)(bias_base + (wn * 4 + mt) * 16 + 4 * g);
        f32x4 bi = {bv.x, bv.y, bv.z, bv.w};
        #pragma unroll
        for (int nt = 0; nt < 4; ++nt) acc[mt][nt] = bi;
    }

    __builtin_amdgcn_s_setprio(1);
    #pragma unroll
    for (int s = 0; s < 8; ++s) {
        f16x8 bh[4], bl[4];
        #pragma unroll
        for (int nt = 0; nt < 4; ++nt) {
            int idx = s * 2048 + g * 512 + (nt * 16 + r15) * 8;
            bh[nt] = *(const f16x8*)&Ahi[idx];
            if (NPASS >= 2) bl[nt] = *(const f16x8*)&Alo[idx];
        }
        #pragma unroll
        for (int mt = 0; mt < 4; ++mt) {
            const _Float16* pb = wbase + s * 8192 + mt * 512;
            f16x8 wh = *(const f16x8*)pb;
            f16x8 wl;
            if (NPASS >= 3) wl = *(const f16x8*)(pb + WLO_OFF);
            #pragma unroll
            for (int nt = 0; nt < 4; ++nt) {
                acc[mt][nt] = __builtin_amdgcn_mfma_f32_16x16x32_f16(wh, bh[nt], acc[mt][nt], 0, 0, 0);
                if (NPASS >= 2)
                    acc[mt][nt] = __builtin_amdgcn_mfma_f32_16x16x32_f16(wh, bl[nt], acc[mt][nt], 0, 0, 0);
                if (NPASS >= 3)
                    acc[mt][nt] = __builtin_amdgcn_mfma_f32_16x16x32_f16(wl, bh[nt], acc[mt][nt], 0, 0, 0);
            }
        }
    }
    __builtin_amdgcn_s_setprio(0);

    // epilogue part 1 (PRE-barrier, registers only): sin (+ split) + pack.
    // chunk s' = 2*wn + a; f16x8: [0..3] = mt 2a (e=0..3), [4..7] = mt 2a+1
    uint4 chv[4][2], clv[4][2];
    #pragma unroll
    for (int nt = 0; nt < 4; ++nt) {
        #pragma unroll
        for (int a = 0; a < 2; ++a) {
            if (WRITE_LO) {
                sin_split_pk(acc[2*a  ][nt][0], acc[2*a  ][nt][1], chv[nt][a].x, clv[nt][a].x);
                sin_split_pk(acc[2*a  ][nt][2], acc[2*a  ][nt][3], chv[nt][a].y, clv[nt][a].y);
                sin_split_pk(acc[2*a+1][nt][0], acc[2*a+1][nt][1], chv[nt][a].z, clv[nt][a].z);
                sin_split_pk(acc[2*a+1][nt][2], acc[2*a+1][nt][3], chv[nt][a].w, clv[nt][a].w);
            } else {
                chv[nt][a].x = sin_pk2(acc[2*a  ][nt][0], acc[2*a  ][nt][1]);
                chv[nt][a].y = sin_pk2(acc[2*a  ][nt][2], acc[2*a  ][nt][3]);
                chv[nt][a].z = sin_pk2(acc[2*a+1][nt][0], acc[2*a+1][nt][1]);
                chv[nt][a].w = sin_pk2(acc[2*a+1][nt][2], acc[2*a+1][nt][3]);
            }
        }
    }

    // epilogue part 2: barrier, then only the vector LDS writes
    __syncthreads();   // all waves done reading old act
    #pragma unroll
    for (int nt = 0; nt < 4; ++nt) {
        int p = nt * 16 + r15;
        #pragma unroll
        for (int a = 0; a < 2; ++a) {
            int idx = (2 * wn + a) * 2048 + g * 512 + p * 8;
            *(uint4*)&Ahi[idx] = chv[nt][a];
            if (WRITE_LO) *(uint4*)&Alo[idx] = clv[nt][a];
        }
    }
    __syncthreads();   // new act visible
}

// D = W(A-op, feats) x act(B-op, points); D col = point, row = feat.
__global__ __launch_bounds__(256, 2)
void siren_mfma(const float* __restrict__ coords,
                const float* __restrict__ w,
                const float* __restrict__ b,
                const _Float16* __restrict__ wf,
                float* __restrict__ out)
{
    __shared__ _Float16 Ahi[64 * 256];
    __shared__ _Float16 Alo[64 * 256];

    const int bid = blockIdx.x, batch = bid >> 8, tile = bid & 255, n0 = tile * 64;
    const int t = threadIdx.x, wn = t >> 6, lane = t & 63;
    const int r15 = lane & 15, g = lane >> 4;

    const float* wb = w + (size_t)batch * W_TOT;
    const float* bb = b + (size_t)batch * B_TOT;

    // ---- layer 0 (entry): 2 -> 256 (VALU), write stream-layout act hi+lo ----
    {
        int p = t >> 2, fb = (t & 3) * 64;
        float2 c = ((const float2*)coords)[(size_t)batch * NPTS + n0 + p];
        #pragma unroll 8
        for (int j2 = 0; j2 < 64; j2 += 2) {
            int f = fb + j2;
            float4 wv = *(const float4*)(wb + 2 * f);
            float b0 = bb[f], b1 = bb[f + 1];
            float u0 = fmaf(c.x, wv.x, fmaf(c.y, wv.y, b0));
            float u1 = fmaf(c.x, wv.z, fmaf(c.y, wv.w, b1));
            unsigned uh, ul;
            sin_split_pk(u0, u1, uh, ul);
            int sf = f >> 5, cf = (f >> 2) & 3, ef = ((f >> 4) & 1) * 4 + (f & 3);
            int idx = sf * 2048 + cf * 512 + p * 8 + ef;   // ef even here
            *(unsigned*)&Ahi[idx] = uh;
            *(unsigned*)&Alo[idx] = ul;
        }
    }
    __syncthreads();

    // ---- hidden layers: 3-pass, 3-pass (hi-only out), 1-pass ----
    // error model (calibrated r11/r12/r13): lh-skip@h1 ~0.17 (fatal, kept);
    // hl-skip@h2 ~0.02 tail (safe, taken); lh-skip@h2 invisible (taken r13).
    hidden_layer<3, true >(Ahi, Alo, wf + (size_t)(batch * 3 + 0) * 65536, bb + 256,       wn, lane, r15, g);
    hidden_layer<3, false>(Ahi, Alo, wf + (size_t)(batch * 3 + 1) * 65536, bb + 256 + 256, wn, lane, r15, g);
    hidden_layer<1, false>(Ahi, Alo, wf + (size_t)(batch * 3 + 2) * 65536, bb + 256 + 512, wn, lane, r15, g);

    // ---- layer 4: 256 -> 3 (hi only) ----
    {
        f32x4 acc4 = {};
        const _Float16* w4 = wf + W4_OFF + batch * 4096;
        #pragma unroll
        for (int s = 0; s < 8; ++s) {
            int p = wn * 16 + r15;
            int idx = s * 2048 + g * 512 + p * 8;
            f16x8 bh = *(const f16x8*)&Ahi[idx];
            f16x8 w4f = *(const f16x8*)(w4 + s * 512 + lane * 8);
            acc4 = __builtin_amdgcn_mfma_f32_16x16x32_f16(w4f, bh, acc4, 0, 0, 0);
        }
        if (g == 0) {   // rows 0..2 = the 3 outputs; col = point
            int p = wn * 16 + r15;
            float* po = out + ((size_t)batch * NPTS + n0 + p) * 3;
            #pragma unroll
            for (int j = 0; j < 3; ++j)
                po[j] = acc4[j] + bb[1024 + j];
        }
    }
}

// ---- fallback fp32 kernel (used only if ws too small) ----
__global__ __launch_bounds__(256, 2)
void siren_fwd_fp32(const float* __restrict__ coords,
                    const float* __restrict__ w,
                    const float* __restrict__ b,
                    float* __restrict__ out)
{
    __shared__ float A[256][64 + 4];
    const int bid = blockIdx.x, batch = bid >> 8, tile = bid & 255;
    const int t = threadIdx.x, n0 = tile * 64;
    const float* wb = w + (size_t)batch * W_TOT;
    const float* bb = b + (size_t)batch * B_TOT;
    const float2* c2 = (const float2*)(coords + (size_t)(batch * NPTS + n0) * 2);
    {
        const float w0 = wb[t * 2 + 0], w1 = wb[t * 2 + 1], b0 = bb[t];
        for (int p = 0; p < 64; ++p) {
            const float2 c = c2[p];
            A[t][p] = fast_sin30(fmaf(c.x, w0, fmaf(c.y, w1, b0)));
        }
    }
    __syncthreads();
    for (int li = 0; li < 3; ++li) {
        const float* Wl = wb + 512 + li * 65536 + t * 256;
        const float bo = bb[256 + li * 256 + t];
        float res[64];
        for (int pb = 0; pb < 2; ++pb) {
            float acc[32];
            #pragma unroll
            for (int i = 0; i < 32; ++i) acc[i] = bo;
            for (int k = 0; k < 256; k += 4) {
                const float4 wv = *(const float4*)(Wl + k);
                #pragma unroll
                for (int kk = 0; kk < 4; ++kk) {
                    const float wk = (&wv.x)[kk];
                    const float* ar = &A[k + kk][pb * 32];
                    #pragma unroll
                    for (int i = 0; i < 32; i += 4) {
                        const float4 a4 = *(const float4*)(ar + i);
                        acc[i + 0] = fmaf(a4.x, wk, acc[i + 0]);
                        acc[i + 1] = fmaf(a4.y, wk, acc[i + 1]);
                        acc[i + 2] = fmaf(a4.z, wk, acc[i + 2]);
                        acc[i + 3] = fmaf(a4.w, wk, acc[i + 3]);
                    }
                }
            }
            #pragma unroll
            for (int i = 0; i < 32; ++i) res[pb * 32 + i] = fast_sin30(acc[i]);
        }
        __syncthreads();
        for (int p = 0; p < 64; p += 4)
            *(float4*)&A[t][p] = make_float4(res[p], res[p+1], res[p+2], res[p+3]);
        __syncthreads();
    }
    if (t < 192) {
        const int o = t >> 6, p = t & 63;
        const float* W4 = wb + 197120 + o * 256;
        float acc = bb[1024 + o];
        for (int k = 0; k < 256; k += 4) {
            const float4 wv = *(const float4*)(W4 + k);
            acc = fmaf(A[k+0][p], wv.x, acc);
            acc = fmaf(A[k+1][p], wv.y, acc);
            acc = fmaf(A[k+2][p], wv.z, acc);
            acc = fmaf(A[k+3][p], wv.w, acc);
        }
        out[(size_t)(batch * NPTS + n0 + p) * 3 + o] = acc;
    }
}

extern "C" void kernel_launch(void* const* d_in, const int* in_sizes, int n_in,
                              void* d_out, int out_size, void* d_ws, size_t ws_size,
                              hipStream_t stream)
{
    const float* coords = (const float*)d_in[0];
    const float* w      = (const float*)d_in[1];
    const float* bvec   = (const float*)d_in[2];
    const float* latent = (const float*)d_in[3];
    float* out = (float*)d_out;

    if (ws_size >= WS_NEEDED) {
        _Float16* wf = (_Float16*)d_ws;
        make_wfrags<<<25088, 256, 0, stream>>>(w, wf);
        siren_mfma<<<NBATCH * (NPTS / 64), 256, 0, stream>>>(coords, w, bvec, wf, out);
    } else {
        siren_fwd_fp32<<<NBATCH * (NPTS / 64), 256, 0, stream>>>(coords, w, bvec, out);
    }

    hipMemcpyAsync(out + OUT_COORDS, coords, (size_t)1048576 * sizeof(float),
                   hipMemcpyDeviceToDevice, stream);
    hipMemcpyAsync(out + OUT_W,      w,      (size_t)6332416 * sizeof(float),
                   hipMemcpyDeviceToDevice, stream);
    hipMemcpyAsync(out + OUT_B,      bvec,   (size_t)32864   * sizeof(float),
                   hipMemcpyDeviceToDevice, stream);
    hipMemcpyAsync(out + OUT_LAT,    latent, (size_t)8192    * sizeof(float),
                   hipMemcpyDeviceToDevice, stream);
}